// Round 2
// baseline (7335.777 us; speedup 1.0000x reference)
//
#include <hip/hip_runtime.h>
#include <hip/hip_fp16.h>

#define R   8192
#define C1  8213
#define C2  8192
#define CP  8216      // padded row stride (halves / floats), multiple of 8

struct __align__(8) h4 { __half2 a, b; };

__device__ __forceinline__ float4 h4tof4(h4 kv) {
    float2 f0 = __half22float2(kv.a);
    float2 f1 = __half22float2(kv.b);
    return make_float4(f0.x, f0.y, f1.x, f1.y);
}

__device__ __forceinline__ float gm_label(float sc, int lab) {
    if (lab == 0) return fmaxf(-0.02f - sc, 0.0f) + fmaxf(sc, 0.0f);
    if (lab == 3) return fmaxf(0.09f + sc, 0.0f);
    return fmaxf(0.05f + sc, 0.0f) + fmaxf(-0.09f - sc, 0.0f); // labels 1|2
}

__device__ __forceinline__ float kval(float gm) {
    // K = exp(-M/REG) with M = exp(-GM), REG = -0.2  ->  exp(5*exp(-GM))
    return expf(5.0f * expf(-gm));
}

// ---- build kernels: K zero-padded to CP columns ----

__global__ __launch_bounds__(256) void build_k1(const float* __restrict__ dist,
                                                const int* __restrict__ lab,
                                                __half* __restrict__ K) {
    int row = blockIdx.y;
    int j0 = (blockIdx.x * 256 + threadIdx.x) * 4;
    if (j0 >= CP) return;          // j0 <= 8212 -> j0+3 <= 8215 < CP
    size_t ib = (size_t)row * C1;
    float d0 = dist[ib];
    float val[4];
#pragma unroll
    for (int k = 0; k < 4; ++k) {
        int j = j0 + k;
        val[k] = 0.0f;
        if (j < C1) {
            float g = gm_label(dist[ib + j] - d0, lab[ib + j]);
            val[k] = kval(g);
        }
    }
    h4 kv;
    kv.a = __floats2half2_rn(val[0], val[1]);
    kv.b = __floats2half2_rn(val[2], val[3]);
    *reinterpret_cast<h4*>(K + (size_t)row * CP + j0) = kv;
}

__global__ __launch_bounds__(256) void diag_k(const float* __restrict__ dist,
                                              float* __restrict__ dcol) {
    int j = blockIdx.x * 256 + threadIdx.x;
    if (j < R) dcol[j] = dist[(size_t)j * C1 + 21 + j];
}

__global__ __launch_bounds__(256) void build_k2(const float* __restrict__ dist,
                                                const float* __restrict__ dcol,
                                                __half* __restrict__ K) {
    int row = blockIdx.y;
    int j0 = (blockIdx.x * 256 + threadIdx.x) * 4;
    if (j0 >= CP) return;
    size_t ib = (size_t)row * C1 + 21;
    float val[4];
#pragma unroll
    for (int k = 0; k < 4; ++k) {
        int j = j0 + k;
        val[k] = 0.0f;
        if (j < C2) {
            float s = dist[ib + j] - dcol[j];
            float g = (j == row) ? 0.0f : fmaxf(0.09f + s, 0.0f);
            val[k] = kval(g);
        }
    }
    h4 kv;
    kv.a = __floats2half2_rn(val[0], val[1]);
    kv.b = __floats2half2_rn(val[2], val[3]);
    *reinterpret_cast<h4*>(K + (size_t)row * CP + j0) = kv;
}

// ---- initial column pass with uniform u = uval ----
__global__ __launch_bounds__(256) void col_partial0(const __half* __restrict__ K,
                                                    float* __restrict__ part,
                                                    int rowsPB, float uval) {
    int tx = threadIdx.x;
    int r0 = blockIdx.x * rowsPB;
    bool tail = tx < 6;
    float4 acc[8];
#pragma unroll
    for (int i = 0; i < 8; ++i) acc[i] = make_float4(0, 0, 0, 0);
    float4 acct = make_float4(0, 0, 0, 0);
    for (int r = 0; r < rowsPB; ++r) {
        const h4* K4 = reinterpret_cast<const h4*>(K + (size_t)(r0 + r) * CP);
#pragma unroll
        for (int i = 0; i < 8; ++i) {
            float4 f = h4tof4(K4[tx + i * 256]);
            acc[i].x += f.x; acc[i].y += f.y; acc[i].z += f.z; acc[i].w += f.w;
        }
        if (tail) {
            float4 f = h4tof4(K4[2048 + tx]);
            acct.x += f.x; acct.y += f.y; acct.z += f.z; acct.w += f.w;
        }
    }
    float4* prow = reinterpret_cast<float4*>(part + (size_t)blockIdx.x * CP);
#pragma unroll
    for (int i = 0; i < 8; ++i) {
        acc[i].x *= uval; acc[i].y *= uval; acc[i].z *= uval; acc[i].w *= uval;
        prow[tx + i * 256] = acc[i];
    }
    if (tail) {
        acct.x *= uval; acct.y *= uval; acct.z *= uval; acct.w *= uval;
        prow[2048 + tx] = acct;
    }
}

// ---- fused iteration: u[i] = aval/rowsum(K[i,:]*v) computed in-block, then
//      partial column sums part[s][j] = sum_{rows in s} u*K  (K stays in regs) ----
__global__ __launch_bounds__(256) void fused_iter(const __half* __restrict__ K,
                                                  const float* __restrict__ v,
                                                  float* __restrict__ part,
                                                  int rowsPB, float aval) {
    __shared__ float rp[2][4][4];
    int tx = threadIdx.x;
    int lane = tx & 63, wv = tx >> 6;
    int r0 = blockIdx.x * rowsPB;
    const float4* v4 = reinterpret_cast<const float4*>(v);
    float4 vv[8];
#pragma unroll
    for (int i = 0; i < 8; ++i) vv[i] = v4[tx + i * 256];
    bool tail = tx < 6;
    float4 vt = make_float4(0, 0, 0, 0);
    if (tail) vt = v4[2048 + tx];
    float4 acc[8];
#pragma unroll
    for (int i = 0; i < 8; ++i) acc[i] = make_float4(0, 0, 0, 0);
    float4 acct = make_float4(0, 0, 0, 0);

    int ngroup = rowsPB >> 2;
    for (int g = 0; g < ngroup; ++g) {
        h4 ch[4][8];
        h4 cht[4];
        float d[4];
#pragma unroll
        for (int rr = 0; rr < 4; ++rr) {
            const h4* K4 = reinterpret_cast<const h4*>(K + (size_t)(r0 + g * 4 + rr) * CP);
            float dot = 0.0f;
#pragma unroll
            for (int i = 0; i < 8; ++i) {
                ch[rr][i] = K4[tx + i * 256];
                float4 f = h4tof4(ch[rr][i]);
                float4 w = vv[i];
                dot = fmaf(f.x, w.x, dot);
                dot = fmaf(f.y, w.y, dot);
                dot = fmaf(f.z, w.z, dot);
                dot = fmaf(f.w, w.w, dot);
            }
            if (tail) {
                cht[rr] = K4[2048 + tx];
                float4 f = h4tof4(cht[rr]);
                dot = fmaf(f.x, vt.x, dot);
                dot = fmaf(f.y, vt.y, dot);
                dot = fmaf(f.z, vt.z, dot);
                dot = fmaf(f.w, vt.w, dot);
            }
            d[rr] = dot;
        }
#pragma unroll
        for (int rr = 0; rr < 4; ++rr) {
#pragma unroll
            for (int off = 32; off; off >>= 1) d[rr] += __shfl_down(d[rr], off, 64);
        }
        if (lane == 0) {
#pragma unroll
            for (int rr = 0; rr < 4; ++rr) rp[g & 1][rr][wv] = d[rr];
        }
        __syncthreads();
#pragma unroll
        for (int rr = 0; rr < 4; ++rr) {
            float rs = rp[g & 1][rr][0] + rp[g & 1][rr][1] + rp[g & 1][rr][2] + rp[g & 1][rr][3];
            float ug = aval / rs;
#pragma unroll
            for (int i = 0; i < 8; ++i) {
                float4 f = h4tof4(ch[rr][i]);
                acc[i].x = fmaf(ug, f.x, acc[i].x);
                acc[i].y = fmaf(ug, f.y, acc[i].y);
                acc[i].z = fmaf(ug, f.z, acc[i].z);
                acc[i].w = fmaf(ug, f.w, acc[i].w);
            }
            if (tail) {
                float4 f = h4tof4(cht[rr]);
                acct.x = fmaf(ug, f.x, acct.x);
                acct.y = fmaf(ug, f.y, acct.y);
                acct.z = fmaf(ug, f.z, acct.z);
                acct.w = fmaf(ug, f.w, acct.w);
            }
        }
    }
    float4* prow = reinterpret_cast<float4*>(part + (size_t)blockIdx.x * CP);
#pragma unroll
    for (int i = 0; i < 8; ++i) prow[tx + i * 256] = acc[i];
    if (tail) prow[2048 + tx] = acct;
}

// ---- v[j] = bval / sum_s part[s][j];  64 cols x 4 split-quarters per block ----
__global__ __launch_bounds__(256) void col_reduce(const float* __restrict__ part,
                                                  float* __restrict__ v, int C,
                                                  float bval, int nsplit) {
    __shared__ float sb[4][64];
    int tx = threadIdx.x;
    int c = tx & 63, q = tx >> 6;
    int j = blockIdx.x * 64 + c;
    int ns4 = nsplit >> 2;
    float s = 0.0f;
    if (j < CP) {
        for (int k = q * ns4; k < (q + 1) * ns4; ++k) s += part[(size_t)k * CP + j];
    }
    sb[q][c] = s;
    __syncthreads();
    if (tx < 64) {
        int jj = blockIdx.x * 64 + tx;
        if (jj < CP) {
            float t = sb[0][tx] + sb[1][tx] + sb[2][tx] + sb[3][tx];
            v[jj] = (jj < C) ? bval / t : 0.0f;
        }
    }
}

// ---- loss reductions ----

__device__ __forceinline__ float2 block_reduce_2(float x, float y, float* sb) {
#pragma unroll
    for (int off = 32; off; off >>= 1) {
        x += __shfl_down(x, off, 64);
        y += __shfl_down(y, off, 64);
    }
    if ((threadIdx.x & 63) == 0) {
        int w = threadIdx.x >> 6;
        sb[w] = x; sb[4 + w] = y;
    }
    __syncthreads();
    float2 r;
    r.x = sb[0] + sb[1] + sb[2] + sb[3];
    r.y = sb[4] + sb[5] + sb[6] + sb[7];
    __syncthreads();
    return r;
}

__global__ __launch_bounds__(256) void loss1_k(const __half* __restrict__ K,
                                               const float* __restrict__ v,
                                               const float* __restrict__ dist,
                                               const int* __restrict__ lab,
                                               float* __restrict__ ratio) {
    __shared__ float sb[8];
    int i = blockIdx.x;
    size_t ib = (size_t)i * C1;
    float d0 = dist[ib];
    const __half* Kr = K + (size_t)i * CP;
    float num = 0, den = 0;
    for (int j = threadIdx.x; j < C1; j += 256) {
        float kv = __half2float(Kr[j]) * v[j];
        float g = gm_label(dist[ib + j] - d0, lab[ib + j]);
        den += kv;
        num = fmaf(g, kv, num);
    }
    float2 r = block_reduce_2(num, den, sb);
    if (threadIdx.x == 0) ratio[i] = r.x / r.y;
}

__global__ __launch_bounds__(256) void loss2_k(const __half* __restrict__ K,
                                               const float* __restrict__ v,
                                               const float* __restrict__ dist,
                                               const float* __restrict__ dcol,
                                               float* __restrict__ ratio) {
    __shared__ float sb[8];
    int i = blockIdx.x;
    const __half* Kr = K + (size_t)i * CP;
    const float* Dr = dist + (size_t)i * C1 + 21;
    float num = 0, den = 0;
    for (int j = threadIdx.x; j < C2; j += 256) {
        if (j == i) continue;
        float kv = __half2float(Kr[j]) * v[j];
        float h = fmaxf(0.09f + Dr[j] - dcol[j], 0.0f);
        den += kv;
        num = fmaf(h, kv, num);
    }
    float2 r = block_reduce_2(num, den, sb);
    if (threadIdx.x == 0) ratio[i] = r.x / r.y;
}

__global__ __launch_bounds__(256) void final_k(const float* __restrict__ r1,
                                               const float* __restrict__ r2,
                                               float* __restrict__ out) {
    __shared__ float sb[8];
    float s1 = 0, s2 = 0;
    for (int i = threadIdx.x; i < R; i += 256) { s1 += r1[i]; s2 += r2[i]; }
    float2 t = block_reduce_2(s1, s2, sb);
    if (threadIdx.x == 0)
        out[0] = t.x / ((float)R * (float)C1) + t.y / ((float)R * (float)C2);
}

static void run_phase(const __half* K, float* v, float* part, int C, int nsplit,
                      hipStream_t stream) {
    float aval = 1.0f / (float)R;
    float bval = 1.0f / (float)C;
    int rowsPB = R / nsplit;
    int gcr = (CP + 63) / 64;   // 129
    col_partial0<<<dim3(nsplit), 256, 0, stream>>>(K, part, rowsPB, aval);
    for (int t = 0; t < 50; ++t) {
        col_reduce<<<dim3(gcr), 256, 0, stream>>>(part, v, C, bval, nsplit);
        if (t < 49)
            fused_iter<<<dim3(nsplit), 256, 0, stream>>>(K, v, part, rowsPB, aval);
    }
}

extern "C" void kernel_launch(void* const* d_in, const int* in_sizes, int n_in,
                              void* d_out, int out_size, void* d_ws, size_t ws_size,
                              hipStream_t stream) {
    const float* dist = (const float*)d_in[0];
    const int* lab = (const int*)d_in[1];
    float* out = (float*)d_out;
    char* ws = (char*)d_ws;

    // pick split count (rows per block = R/nsplit); shrink if workspace is tight
    int nsplit = 512;
    auto need = [](int ns) {
        return (size_t)R * CP * sizeof(__half)       // K
             + (size_t)ns * CP * sizeof(float)       // part
             + (size_t)CP * sizeof(float)            // v
             + 3 * (size_t)R * sizeof(float);        // dcol, rat1, rat2
    };
    while (nsplit > 64 && ws_size < need(nsplit)) nsplit >>= 1;
    if (ws_size < need(nsplit)) return;

    size_t off = 0;
    __half* K = (__half*)(ws + off);   off += (size_t)R * CP * sizeof(__half);
    float* part = (float*)(ws + off);  off += (size_t)nsplit * CP * sizeof(float);
    float* v = (float*)(ws + off);     off += (size_t)CP * sizeof(float);
    float* dcol = (float*)(ws + off);  off += (size_t)R * sizeof(float);
    float* rat1 = (float*)(ws + off);  off += (size_t)R * sizeof(float);
    float* rat2 = (float*)(ws + off);  off += (size_t)R * sizeof(float);

    int gb = (CP + 1023) / 1024;  // 9

    // ---- phase 1 ----
    build_k1<<<dim3(gb, R), 256, 0, stream>>>(dist, lab, K);
    run_phase(K, v, part, C1, nsplit, stream);
    loss1_k<<<dim3(R), 256, 0, stream>>>(K, v, dist, lab, rat1);

    // ---- phase 2 (reuses K buffer) ----
    diag_k<<<dim3((R + 255) / 256), 256, 0, stream>>>(dist, dcol);
    build_k2<<<dim3(gb, R), 256, 0, stream>>>(dist, dcol, K);
    run_phase(K, v, part, C2, nsplit, stream);
    loss2_k<<<dim3(R), 256, 0, stream>>>(K, v, dist, dcol, rat2);

    final_k<<<dim3(1), 256, 0, stream>>>(rat1, rat2, out);
}